// Round 9
// baseline (294.170 us; speedup 1.0000x reference)
//
#include <hip/hip_runtime.h>
#include <cstdint>
#include <cstddef>

#define N_PTS   16384
#define K_CODES 8192
#define DIM     256
#define DECAYF  0.99f
#define OMDF    0.01f
#define EPSF    1e-5f

// output layout (float32, concatenated in reference return order)
#define OFF_ZQ   0
#define OFF_LOSS 4194304
#define OFF_IDX  4194305
#define OFF_W    4210689
#define OFF_CS   6307841
#define OFF_EA   6316033

// scratch parked inside output regions that are written later:
//  zb  = bf16[16384*256] at out+OFF_ZQ            (8 MB, = 128*z)  } z_q region,
//  wb  = bf16[ 8192*256] at out+OFF_ZQ+2097152    (4 MB)           } dead after
//  hen = f32 [ 8192]     at out+OFF_ZQ+3145728    (32 KB)          } k_gemm
//  c1,c2 = u32[64][16384] x2 at out+OFF_W         (8 MB exact fit; k_gather last)
#define ZB_OFF   OFF_ZQ
#define WB_OFF   (OFF_ZQ + 2097152)
#define HEN_OFF  (OFF_ZQ + 3145728)
#define C1_OFF   OFF_W
#define C2_OFF   (OFF_W + 1048576)

typedef __attribute__((ext_vector_type(8))) short bf16x8;
typedef __attribute__((ext_vector_type(4))) float f32x4;

__device__ inline unsigned short f2b(float f) {  // fp32 -> bf16 bits, RNE
    unsigned u = __float_as_uint(f);
    return (unsigned short)((u + 0x7FFFu + ((u >> 16) & 1u)) >> 16);
}

__device__ inline unsigned umaxu(unsigned a, unsigned b) { return a > b ? a : b; }
__device__ inline unsigned uminu(unsigned a, unsigned b) { return a < b ? a : b; }

__device__ inline void gload16(const void* g, void* l) {
    __builtin_amdgcn_global_load_lds(
        (const __attribute__((address_space(1))) unsigned int*)g,
        (__attribute__((address_space(3))) unsigned int*)l, 16, 0, 0);
}

// ---- 1. fp32 -> bf16 (z scaled by 128), fused hen + cnt zero ----------------
__global__ void k_cvt2(const float* __restrict__ z, short* __restrict__ zb,
                       const float* __restrict__ w, short* __restrict__ wb,
                       float* __restrict__ hen, unsigned* __restrict__ cnt) {
    const int tid = threadIdx.x;
    if (blockIdx.x < N_PTS * DIM / 2048) {
        size_t base = (size_t)(blockIdx.x * 256 + tid) * 8;
        float4 a = *(const float4*)(z + base);
        float4 b = *(const float4*)(z + base + 4);
        bf16x8 o;                                   // zb = 128*z (exact scale)
        o[0] = (short)f2b(128.f * a.x); o[1] = (short)f2b(128.f * a.y);
        o[2] = (short)f2b(128.f * a.z); o[3] = (short)f2b(128.f * a.w);
        o[4] = (short)f2b(128.f * b.x); o[5] = (short)f2b(128.f * b.y);
        o[6] = (short)f2b(128.f * b.z); o[7] = (short)f2b(128.f * b.w);
        *(bf16x8*)(zb + base) = o;
    } else {
        int blk = blockIdx.x - N_PTS * DIM / 2048;
        size_t base = (size_t)(blk * 256 + tid) * 8;
        float4 a = *(const float4*)(w + base);
        float4 b = *(const float4*)(w + base + 4);
        bf16x8 o;
        o[0] = (short)f2b(a.x); o[1] = (short)f2b(a.y);
        o[2] = (short)f2b(a.z); o[3] = (short)f2b(a.w);
        o[4] = (short)f2b(b.x); o[5] = (short)f2b(b.y);
        o[6] = (short)f2b(b.z); o[7] = (short)f2b(b.w);
        *(bf16x8*)(wb + base) = o;
        float s = a.x * a.x + a.y * a.y + a.z * a.z + a.w * a.w
                + b.x * b.x + b.y * b.y + b.z * b.z + b.w * b.w;
        #pragma unroll
        for (int m = 16; m >= 1; m >>= 1) s += __shfl_xor(s, m, 64);
        if ((tid & 31) == 0) hen[base >> 8] = 0.5f * s;
        int gid = blk * 256 + tid;
        if (gid < K_CODES) cnt[gid] = 0u;
    }
}

// ---- 2. bf16 MFMA GEMM + top-2 candidates per (z, 128-code tile) ------------
// 256z x 128k block tile, 4 waves stacked in z (wave-tile 64z x 128k),
// acc 4x8 f32x4 = 128 AGPRs; single live B-fragment + __launch_bounds__(256,2)
// -> ~195 unified regs, 2 waves/SIMD. ds:MFMA per kk-step = 12 reads : 32 MFMA
// (balanced pipes). c1/c2 kt-major: each block writes 256 consecutive u32.
__global__ __launch_bounds__(256, 2) void k_gemm(const short* __restrict__ zb,
                                                 const short* __restrict__ wb,
                                                 const float* __restrict__ hen,
                                                 unsigned* __restrict__ c1,
                                                 unsigned* __restrict__ c2) {
    __shared__ __align__(16) short As[256 * 64];   // 32 KB
    __shared__ __align__(16) short Bs[128 * 64];   // 16 KB

    const int tid  = threadIdx.x;
    const int lane = tid & 63;
    const int wv   = tid >> 6;
    const int ztile = blockIdx.x & 63;       // kt-major: 64 blocks share B-tile
    const int kt    = blockIdx.x >> 6;       // 0..63
    const int z0 = ztile * 256, k0 = kt * 128;
    const int col = lane & 15;

    f32x4 acc[4][8];
    #pragma unroll
    for (int ni = 0; ni < 8; ni++) {
        float h = 131072.0f - 128.0f * hen[k0 + ni * 16 + col];
        f32x4 iv = {h, h, h, h};
        #pragma unroll
        for (int mi = 0; mi < 4; mi++) acc[mi][ni] = iv;
    }
    const unsigned inv0 = (unsigned)(K_CODES - 1 - (k0 + col));

    const int srow = lane >> 3;                       // 0..7 within segment
    const int scol = ((lane & 7) ^ srow) * 8;         // swizzled source chunk

    #pragma unroll
    for (int dc = 0; dc < 4; ++dc) {
        __syncthreads();
        #pragma unroll
        for (int s8 = 0; s8 < 8; ++s8) {
            int seg = wv * 8 + s8;                    // A: 32 segments of 8 rows
            gload16(zb + (size_t)(z0 + seg * 8 + srow) * DIM + dc * 64 + scol,
                    As + seg * 512 + lane * 8);
        }
        #pragma unroll
        for (int s4 = 0; s4 < 4; ++s4) {
            int seg = wv * 4 + s4;                    // B: 16 segments of 8 rows
            gload16(wb + (size_t)(k0 + seg * 8 + srow) * DIM + dc * 64 + scol,
                    Bs + seg * 512 + lane * 8);
        }
        __syncthreads();
        #pragma unroll
        for (int kk = 0; kk < 2; ++kk) {
            int ch = ((kk << 2) + (lane >> 4)) ^ (lane & 7);   // de-swizzle
            bf16x8 af[4];
            #pragma unroll
            for (int mi = 0; mi < 4; mi++)
                af[mi] = *(const bf16x8*)&As[(wv * 64 + mi * 16 + col) * 64 + ch * 8];
            #pragma unroll
            for (int ni = 0; ni < 8; ni++) {
                bf16x8 b = *(const bf16x8*)&Bs[(ni * 16 + col) * 64 + ch * 8];
                #pragma unroll
                for (int mi = 0; mi < 4; mi++)
                    acc[mi][ni] = __builtin_amdgcn_mfma_f32_16x16x32_bf16(
                        af[mi], b, acc[mi][ni], 0, 0, 0);
            }
        }
    }

    // epilogue: per z-row top-2 of 128 codes, coalesced kt-major writes
    #pragma unroll
    for (int mi = 0; mi < 4; mi++) {
        #pragma unroll
        for (int r = 0; r < 4; r++) {
            unsigned k8[8];
            #pragma unroll
            for (int ni = 0; ni < 8; ni++) {
                unsigned q = (unsigned)acc[mi][ni][r];         // v_cvt_u32_f32
                k8[ni] = (q << 13) | (inv0 - 16u * ni);        // v_lshl_or_b32
            }
            unsigned p1 = umaxu(k8[0], k8[1]), q1 = uminu(k8[0], k8[1]);
            unsigned p2 = umaxu(k8[2], k8[3]), q2 = uminu(k8[2], k8[3]);
            unsigned p3 = umaxu(k8[4], k8[5]), q3 = uminu(k8[4], k8[5]);
            unsigned p4 = umaxu(k8[6], k8[7]), q4 = uminu(k8[6], k8[7]);
            unsigned a1 = umaxu(p1, p2);
            unsigned a2 = umaxu(uminu(p1, p2), umaxu(q1, q2));
            unsigned b1 = umaxu(p3, p4);
            unsigned b2 = umaxu(uminu(p3, p4), umaxu(q3, q4));
            unsigned t1 = umaxu(a1, b1);
            unsigned t2 = umaxu(uminu(a1, b1), umaxu(a2, b2));
            unsigned m1 = t1;
            #pragma unroll
            for (int m = 8; m >= 1; m >>= 1)
                m1 = umaxu(m1, (unsigned)__shfl_xor((int)m1, m, 64));
            unsigned cc = (t1 == m1) ? t2 : t1;     // keys unique (code id bits)
            #pragma unroll
            for (int m = 8; m >= 1; m >>= 1)
                cc = umaxu(cc, (unsigned)__shfl_xor((int)cc, m, 64));
            if (col == 0) {
                int row = wv * 64 + mi * 16 + (lane >> 4) * 4 + r;
                c1[(size_t)kt * N_PTS + z0 + row] = m1;
                c2[(size_t)kt * N_PTS + z0 + row] = cc;
            }
        }
    }
}

// ---- 3. rescore: LDS-staged keys, gap fast path + fp32 window rescore -------
// 1024-thread blocks; block stages keys for 16 wids (fully coalesced reads of
// the kt-major c1/c2), pad-17 layout -> conflict-free; one wave per wid.
__global__ __launch_bounds__(1024) void k_rescore(
        const float* __restrict__ z, const float* __restrict__ w,
        const unsigned* __restrict__ c1, const unsigned* __restrict__ c2,
        float* __restrict__ out,
        unsigned* __restrict__ cnt, float* __restrict__ lossp) {
    __shared__ unsigned s1[64 * 17], s2[64 * 17];   // 8.5 KB
    const int t  = threadIdx.x;
    const int w0 = blockIdx.x * 16;
    {
        int kt = t >> 4, wo = t & 15;               // 64-B line per 16 threads
        s1[kt * 17 + wo] = c1[(size_t)kt * N_PTS + w0 + wo];
        s2[kt * 17 + wo] = c2[(size_t)kt * N_PTS + w0 + wo];
    }
    __syncthreads();
    const int wv   = t >> 6;       // 0..15 -> wid
    const int lane = t & 63;       // = kt
    const int wid  = w0 + wv;
    float4 zv  = *(const float4*)(z + (size_t)wid * DIM + lane * 4);
    unsigned k1 = s1[lane * 17 + wv];
    unsigned k2 = s2[lane * 17 + wv];

    // global best m1 and runner-up m2 over all 128 keys (k1 >= k2 per lane)
    unsigned m1 = k1;
    #pragma unroll
    for (int m = 32; m >= 1; m >>= 1)
        m1 = umaxu(m1, (unsigned)__shfl_xor((int)m1, m, 64));
    unsigned e = (k1 == m1) ? k2 : k1;
    unsigned m2 = e;
    #pragma unroll
    for (int m = 32; m >= 1; m >>= 1)
        m2 = umaxu(m2, (unsigned)__shfl_xor((int)m2, m, 64));

    int idx = K_CODES - 1 - (int)(m1 & 0x1FFFu);
    // prefetch presumed winner row before the branch
    float4 bw = *(const float4*)(w + (size_t)idx * DIM + lane * 4);

    unsigned qthr = (m1 >> 13) - 96u;     // 0.75 fp32-score window
    if ((m2 >> 13) >= qthr) {             // wave-uniform slow path (~20%)
        unsigned long long best = 0ULL;
        #pragma unroll
        for (int j = 0; j < 2; j++) {
            unsigned cj = j ? k2 : k1;
            unsigned long long mask = __ballot((cj >> 13) >= qthr);
            while (mask) {
                int l = __ffsll((unsigned long long)mask) - 1;
                mask &= mask - 1;
                unsigned cwd = (unsigned)__shfl((int)cj, l, 64);
                int k = K_CODES - 1 - (int)(cwd & 0x1FFFu);
                float4 wr = *(const float4*)(w + (size_t)k * DIM + lane * 4);
                float s = zv.x * wr.x + zv.y * wr.y + zv.z * wr.z + zv.w * wr.w;
                float h = wr.x * wr.x + wr.y * wr.y + wr.z * wr.z + wr.w * wr.w;
                #pragma unroll
                for (int m = 32; m >= 1; m >>= 1) {
                    s += __shfl_xor(s, m, 64);
                    h += __shfl_xor(h, m, 64);
                }
                float sc = s - 0.5f * h;
                unsigned u = __float_as_uint(sc);
                u = (u & 0x80000000u) ? ~u : (u | 0x80000000u);
                unsigned long long key = ((unsigned long long)u << 32)
                                       | (unsigned)(K_CODES - 1 - k);
                if (key > best) best = key;
            }
        }
        int nidx = K_CODES - 1 - (int)(unsigned)(best & 0xFFFFFFFFull);
        if (nidx != idx) {                // wave-uniform; rare
            idx = nidx;
            bw = *(const float4*)(w + (size_t)idx * DIM + lane * 4);
        }
    }

    *(float4*)(out + OFF_ZQ + (size_t)wid * DIM + lane * 4) = bw;

    float dx = bw.x - zv.x, dy = bw.y - zv.y, dz = bw.z - zv.z, dw = bw.w - zv.w;
    float s2v = dx * dx + dy * dy + dz * dz + dw * dw;
    #pragma unroll
    for (int m = 32; m >= 1; m >>= 1) s2v += __shfl_xor(s2v, m, 64);

    if (lane == 0) {
        out[OFF_IDX + wid] = (float)idx;
        lossp[wid] = s2v;
        atomicAdd(cnt + idx, 1u);
    }
}

// ---- 4. single-block: scan + new_cs + n + loss + fill (cursor in LDS) -------
__global__ __launch_bounds__(1024) void k_prefix(const float* __restrict__ csin,
                                                 float* __restrict__ out,
                                                 const unsigned* __restrict__ cnt,
                                                 unsigned* __restrict__ offs,
                                                 unsigned* __restrict__ list,
                                                 const float* __restrict__ lossp,
                                                 float* __restrict__ nval) {
    __shared__ unsigned scur[K_CODES];     // 32 KB LDS cursor
    __shared__ unsigned wtot[16], wbase[16];
    __shared__ float fred[16], fred2[16];
    int t = threadIdx.x, lane = t & 63, wv = t >> 6;
    int base = t * 8;
    unsigned c[8], mysum = 0;
    #pragma unroll
    for (int i = 0; i < 8; i++) { c[i] = cnt[base + i]; mysum += c[i]; }
    unsigned inc = mysum;
    #pragma unroll
    for (int off = 1; off < 64; off <<= 1) {
        unsigned v = (unsigned)__shfl_up((int)inc, off, 64);
        if (lane >= off) inc += v;
    }
    if (lane == 63) wtot[wv] = inc;
    __syncthreads();
    if (t == 0) {
        unsigned r = 0;
        for (int i = 0; i < 16; i++) { wbase[i] = r; r += wtot[i]; }
        offs[K_CODES] = r;
    }
    __syncthreads();
    unsigned my0 = wbase[wv] + inc - mysum;
    float csl = 0.f;
    #pragma unroll
    for (int i = 0; i < 8; i++) {
        offs[base + i] = my0;
        scur[base + i] = my0;
        my0 += c[i];
        float ncs = DECAYF * csin[base + i] + OMDF * (float)c[i];
        out[OFF_CS + base + i] = ncs;
        csl += ncs;
    }
    #pragma unroll
    for (int m = 32; m >= 1; m >>= 1) csl += __shfl_xor(csl, m, 64);
    if (lane == 0) fred[wv] = csl;
    float lp = 0.f;
    #pragma unroll
    for (int i = 0; i < 16; i++) lp += lossp[t + i * 1024];
    #pragma unroll
    for (int m = 32; m >= 1; m >>= 1) lp += __shfl_xor(lp, m, 64);
    if (lane == 0) fred2[wv] = lp;
    __syncthreads();
    if (t == 0) {
        float n = 0.f, L = 0.f;
        for (int i = 0; i < 16; i++) { n += fred[i]; L += fred2[i]; }
        *nval = n;
        out[OFF_LOSS] = L * (1.0f / ((float)N_PTS * DIM));
    }
    // fill phase: LDS-atomic cursors, scattered list writes
    for (int i = t; i < N_PTS; i += 1024) {
        int idx = (int)out[OFF_IDX + i];
        unsigned pos = atomicAdd(&scur[idx], 1u);
        list[pos] = (unsigned)i;
    }
}

// ---- 5. per-code gather: new_ea and new_weight rows (no atomics) ------------
__global__ void k_gather(const float* __restrict__ z, const float* __restrict__ ea,
                         float* __restrict__ out,
                         const unsigned* __restrict__ offs,
                         const unsigned* __restrict__ list,
                         const float* __restrict__ nval) {
    int k = blockIdx.x, lane = threadIdx.x;
    unsigned beg = offs[k], end = offs[k + 1];
    float4 acc = {0.f, 0.f, 0.f, 0.f};
    for (unsigned p = beg; p < end; ++p) {
        unsigned i = list[p];
        float4 zv = *(const float4*)(z + (size_t)i * DIM + lane * 4);
        acc.x += zv.x; acc.y += zv.y; acc.z += zv.z; acc.w += zv.w;
    }
    float4 e = *(const float4*)(ea + (size_t)k * DIM + lane * 4);
    e.x = DECAYF * e.x + OMDF * acc.x;
    e.y = DECAYF * e.y + OMDF * acc.y;
    e.z = DECAYF * e.z + OMDF * acc.z;
    e.w = DECAYF * e.w + OMDF * acc.w;
    *(float4*)(out + OFF_EA + (size_t)k * DIM + lane * 4) = e;

    float cs = out[OFF_CS + k];
    float n  = *nval;
    float inv = 1.f / ((cs + EPSF) / (n + (float)K_CODES * EPSF) * n);
    float4 wr = {e.x * inv, e.y * inv, e.z * inv, e.w * inv};
    *(float4*)(out + OFF_W + (size_t)k * DIM + lane * 4) = wr;
}

extern "C" void kernel_launch(void* const* d_in, const int* in_sizes, int n_in,
                              void* d_out, int out_size, void* d_ws, size_t ws_size,
                              hipStream_t stream) {
    const float* z  = (const float*)d_in[0];
    const float* w  = (const float*)d_in[1];
    const float* cs = (const float*)d_in[2];
    const float* ea = (const float*)d_in[3];
    float* out = (float*)d_out;

    short*    zb  = (short*)(out + ZB_OFF);
    short*    wb  = (short*)(out + WB_OFF);
    float*    hen = out + HEN_OFF;
    unsigned* c1  = (unsigned*)(out + C1_OFF);
    unsigned* c2  = (unsigned*)(out + C2_OFF);

    // small scratch in d_ws (~170 KB)
    unsigned* cnt   = (unsigned*)d_ws;        // 8192
    unsigned* offs  = cnt + 8192;             // 8193 (padded to 8200)
    unsigned* list  = offs + 8200;            // 16384
    float*    lossp = (float*)(list + 16384); // 16384
    float*    nval  = lossp + 16384;          // 1

    hipLaunchKernelGGL(k_cvt2,    dim3((N_PTS + K_CODES) * DIM / 2048), dim3(256), 0, stream,
                       z, zb, w, wb, hen, cnt);
    hipLaunchKernelGGL(k_gemm,    dim3((N_PTS / 256) * (K_CODES / 128)), dim3(256), 0, stream,
                       zb, wb, hen, c1, c2);
    hipLaunchKernelGGL(k_rescore, dim3(N_PTS / 16),           dim3(1024), 0, stream,
                       z, w, c1, c2, out, cnt, lossp);
    hipLaunchKernelGGL(k_prefix,  dim3(1),                    dim3(1024), 0, stream,
                       cs, out, cnt, offs, list, lossp, nval);
    hipLaunchKernelGGL(k_gather,  dim3(K_CODES),              dim3(64), 0, stream,
                       z, ea, out, offs, list, nval);
}

// Round 10
// 277.959 us; speedup vs baseline: 1.0583x; 1.0583x over previous
//
#include <hip/hip_runtime.h>
#include <cstdint>
#include <cstddef>

#define N_PTS   16384
#define K_CODES 8192
#define DIM     256
#define DECAYF  0.99f
#define OMDF    0.01f
#define EPSF    1e-5f

// output layout (float32, concatenated in reference return order)
#define OFF_ZQ   0
#define OFF_LOSS 4194304
#define OFF_IDX  4194305
#define OFF_W    4210689
#define OFF_CS   6307841
#define OFF_EA   6316033

// scratch parked inside output regions that are written later:
//  zb  = bf16[16384*256] at out+OFF_ZQ            (8 MB, = 128*z)  } z_q region,
//  wb  = bf16[ 8192*256] at out+OFF_ZQ+2097152    (4 MB)           } dead after
//  hen = f32 [ 8192]     at out+OFF_ZQ+3145728    (32 KB)          } k_gemm
//  c1,c2 = u32[64][16384] x2 at out+OFF_W         (8 MB exact fit; dead after
//                                                  k_rescore; k_gather rewrites)
#define ZB_OFF   OFF_ZQ
#define WB_OFF   (OFF_ZQ + 2097152)
#define HEN_OFF  (OFF_ZQ + 3145728)
#define C1_OFF   OFF_W
#define C2_OFF   (OFF_W + 1048576)

typedef __attribute__((ext_vector_type(8))) short bf16x8;
typedef __attribute__((ext_vector_type(4))) float f32x4;

__device__ inline unsigned short f2b(float f) {  // fp32 -> bf16 bits, RNE
    unsigned u = __float_as_uint(f);
    return (unsigned short)((u + 0x7FFFu + ((u >> 16) & 1u)) >> 16);
}

__device__ inline unsigned umaxu(unsigned a, unsigned b) { return a > b ? a : b; }
__device__ inline unsigned uminu(unsigned a, unsigned b) { return a < b ? a : b; }

__device__ inline void gload16(const void* g, void* l) {
    __builtin_amdgcn_global_load_lds(
        (const __attribute__((address_space(1))) unsigned int*)g,
        (__attribute__((address_space(3))) unsigned int*)l, 16, 0, 0);
}

// ---- 1. fp32 -> bf16 (z scaled by 128) + per-point ||z||^2 + hen + cnt zero -
__global__ void k_cvt2(const float* __restrict__ z, short* __restrict__ zb,
                       const float* __restrict__ w, short* __restrict__ wb,
                       float* __restrict__ hen, unsigned* __restrict__ cnt,
                       float* __restrict__ zn2) {
    const int tid = threadIdx.x;
    if (blockIdx.x < N_PTS * DIM / 2048) {
        size_t base = (size_t)(blockIdx.x * 256 + tid) * 8;
        float4 a = *(const float4*)(z + base);
        float4 b = *(const float4*)(z + base + 4);
        bf16x8 o;                                   // zb = 128*z (exact scale)
        o[0] = (short)f2b(128.f * a.x); o[1] = (short)f2b(128.f * a.y);
        o[2] = (short)f2b(128.f * a.z); o[3] = (short)f2b(128.f * a.w);
        o[4] = (short)f2b(128.f * b.x); o[5] = (short)f2b(128.f * b.y);
        o[6] = (short)f2b(128.f * b.z); o[7] = (short)f2b(128.f * b.w);
        *(bf16x8*)(zb + base) = o;
        // per-point ||z||^2 (32 threads per point)
        float s = a.x * a.x + a.y * a.y + a.z * a.z + a.w * a.w
                + b.x * b.x + b.y * b.y + b.z * b.z + b.w * b.w;
        #pragma unroll
        for (int m = 16; m >= 1; m >>= 1) s += __shfl_xor(s, m, 64);
        if ((tid & 31) == 0) zn2[blockIdx.x * 8 + (tid >> 5)] = s;
    } else {
        int blk = blockIdx.x - N_PTS * DIM / 2048;
        size_t base = (size_t)(blk * 256 + tid) * 8;
        float4 a = *(const float4*)(w + base);
        float4 b = *(const float4*)(w + base + 4);
        bf16x8 o;
        o[0] = (short)f2b(a.x); o[1] = (short)f2b(a.y);
        o[2] = (short)f2b(a.z); o[3] = (short)f2b(a.w);
        o[4] = (short)f2b(b.x); o[5] = (short)f2b(b.y);
        o[6] = (short)f2b(b.z); o[7] = (short)f2b(b.w);
        *(bf16x8*)(wb + base) = o;
        float s = a.x * a.x + a.y * a.y + a.z * a.z + a.w * a.w
                + b.x * b.x + b.y * b.y + b.z * b.z + b.w * b.w;
        #pragma unroll
        for (int m = 16; m >= 1; m >>= 1) s += __shfl_xor(s, m, 64);
        if ((tid & 31) == 0) hen[base >> 8] = 0.5f * s;
        int gid = blk * 256 + tid;
        if (gid < K_CODES) cnt[gid] = 0u;
    }
}

// ---- 2. bf16 MFMA GEMM + top-2 candidates per (z, 128-code tile) ------------
// round-8 proven config: 128z x 128k tile, 4 waves stacked in z (32z x 128k),
// acc 2x8 = 64 AGPRs, single live B-fragment, __launch_bounds__(256,4),
// kt-major coalesced c1/c2 writes. 97 us measured.
__global__ __launch_bounds__(256, 4) void k_gemm(const short* __restrict__ zb,
                                                 const short* __restrict__ wb,
                                                 const float* __restrict__ hen,
                                                 unsigned* __restrict__ c1,
                                                 unsigned* __restrict__ c2) {
    __shared__ __align__(16) short As[128 * 64];   // 16 KB
    __shared__ __align__(16) short Bs[128 * 64];   // 16 KB

    const int tid  = threadIdx.x;
    const int lane = tid & 63;
    const int wv   = tid >> 6;
    const int ztile = blockIdx.x & 127;      // kt-major: 128 blocks share B-tile
    const int kt    = blockIdx.x >> 7;       // 0..63
    const int z0 = ztile * 128, k0 = kt * 128;
    const int col = lane & 15;

    f32x4 acc[2][8];
    #pragma unroll
    for (int ni = 0; ni < 8; ni++) {
        float h = 131072.0f - 128.0f * hen[k0 + ni * 16 + col];
        f32x4 iv = {h, h, h, h};
        acc[0][ni] = iv; acc[1][ni] = iv;
    }
    const unsigned inv0 = (unsigned)(K_CODES - 1 - (k0 + col));

    const int srow = lane >> 3;                       // 0..7 within segment
    const int scol = ((lane & 7) ^ srow) * 8;         // swizzled source chunk

    #pragma unroll
    for (int dc = 0; dc < 4; ++dc) {
        __syncthreads();
        #pragma unroll
        for (int s4 = 0; s4 < 4; ++s4) {
            int seg = wv * 4 + s4;                    // 16 segments of 8 rows
            gload16(zb + (size_t)(z0 + seg * 8 + srow) * DIM + dc * 64 + scol,
                    As + seg * 512 + lane * 8);
            gload16(wb + (size_t)(k0 + seg * 8 + srow) * DIM + dc * 64 + scol,
                    Bs + seg * 512 + lane * 8);
        }
        __syncthreads();
        #pragma unroll
        for (int kk = 0; kk < 2; ++kk) {
            int ch = ((kk << 2) + (lane >> 4)) ^ (lane & 7);   // de-swizzle
            bf16x8 a0 = *(const bf16x8*)&As[(wv * 32 + col) * 64 + ch * 8];
            bf16x8 a1 = *(const bf16x8*)&As[(wv * 32 + 16 + col) * 64 + ch * 8];
            #pragma unroll
            for (int ni = 0; ni < 8; ni++) {
                bf16x8 b = *(const bf16x8*)&Bs[(ni * 16 + col) * 64 + ch * 8];
                acc[0][ni] = __builtin_amdgcn_mfma_f32_16x16x32_bf16(
                    a0, b, acc[0][ni], 0, 0, 0);
                acc[1][ni] = __builtin_amdgcn_mfma_f32_16x16x32_bf16(
                    a1, b, acc[1][ni], 0, 0, 0);
            }
        }
    }

    // epilogue: per z-row top-2 of 128 codes, coalesced kt-major writes
    #pragma unroll
    for (int mi = 0; mi < 2; mi++) {
        #pragma unroll
        for (int r = 0; r < 4; r++) {
            unsigned k8[8];
            #pragma unroll
            for (int ni = 0; ni < 8; ni++) {
                unsigned q = (unsigned)acc[mi][ni][r];         // v_cvt_u32_f32
                k8[ni] = (q << 13) | (inv0 - 16u * ni);        // v_lshl_or_b32
            }
            unsigned p1 = umaxu(k8[0], k8[1]), q1 = uminu(k8[0], k8[1]);
            unsigned p2 = umaxu(k8[2], k8[3]), q2 = uminu(k8[2], k8[3]);
            unsigned p3 = umaxu(k8[4], k8[5]), q3 = uminu(k8[4], k8[5]);
            unsigned p4 = umaxu(k8[6], k8[7]), q4 = uminu(k8[6], k8[7]);
            unsigned a1 = umaxu(p1, p2);
            unsigned a2 = umaxu(uminu(p1, p2), umaxu(q1, q2));
            unsigned b1 = umaxu(p3, p4);
            unsigned b2 = umaxu(uminu(p3, p4), umaxu(q3, q4));
            unsigned t1 = umaxu(a1, b1);
            unsigned t2 = umaxu(uminu(a1, b1), umaxu(a2, b2));
            unsigned m1 = t1;
            #pragma unroll
            for (int m = 8; m >= 1; m >>= 1)
                m1 = umaxu(m1, (unsigned)__shfl_xor((int)m1, m, 64));
            unsigned cc = (t1 == m1) ? t2 : t1;     // keys unique (code id bits)
            #pragma unroll
            for (int m = 8; m >= 1; m >>= 1)
                cc = umaxu(cc, (unsigned)__shfl_xor((int)cc, m, 64));
            if (col == 0) {
                int row = wv * 32 + mi * 16 + (lane >> 4) * 4 + r;
                c1[(size_t)kt * N_PTS + z0 + row] = m1;
                c2[(size_t)kt * N_PTS + z0 + row] = cc;
            }
        }
    }
}

// ---- 3. rescore: idx + loss only (no z read, no z_q write, no fast-path w) --
// loss identity: ||z - w||^2 = ||z||^2 - 2*score. Fast path uses the quantized
// key score ((q - 131072)/128, error <= 1/128 + bf16 noise -> ~3e-5 on final
// mean loss). Slow path tracks the winner's fp32 score.
__global__ __launch_bounds__(1024) void k_rescore(
        const float* __restrict__ z, const float* __restrict__ w,
        const unsigned* __restrict__ c1, const unsigned* __restrict__ c2,
        const float* __restrict__ zn2,
        float* __restrict__ out,
        unsigned* __restrict__ cnt, float* __restrict__ lossp) {
    __shared__ unsigned s1[64 * 17], s2[64 * 17];   // 8.5 KB
    const int t  = threadIdx.x;
    const int w0 = blockIdx.x * 16;
    {
        int kt = t >> 4, wo = t & 15;               // 64-B line per 16 threads
        s1[kt * 17 + wo] = c1[(size_t)kt * N_PTS + w0 + wo];
        s2[kt * 17 + wo] = c2[(size_t)kt * N_PTS + w0 + wo];
    }
    __syncthreads();
    const int wv   = t >> 6;       // 0..15 -> wid
    const int lane = t & 63;       // = kt
    const int wid  = w0 + wv;
    unsigned k1 = s1[lane * 17 + wv];
    unsigned k2 = s2[lane * 17 + wv];

    // global best m1 and runner-up m2 over all 128 keys (k1 >= k2 per lane)
    unsigned m1 = k1;
    #pragma unroll
    for (int m = 32; m >= 1; m >>= 1)
        m1 = umaxu(m1, (unsigned)__shfl_xor((int)m1, m, 64));
    unsigned e = (k1 == m1) ? k2 : k1;
    unsigned m2 = e;
    #pragma unroll
    for (int m = 32; m >= 1; m >>= 1)
        m2 = umaxu(m2, (unsigned)__shfl_xor((int)m2, m, 64));

    int idx = K_CODES - 1 - (int)(m1 & 0x1FFFu);
    float scf = ((float)(int)(m1 >> 13) - 131072.0f) * 0.0078125f;

    unsigned qthr = (m1 >> 13) - 96u;     // 0.75 fp32-score window
    if ((m2 >> 13) >= qthr) {             // wave-uniform slow path (~20%)
        unsigned long long best = 0ULL;
        float bsc = 0.f;
        #pragma unroll
        for (int j = 0; j < 2; j++) {
            unsigned cj = j ? k2 : k1;
            unsigned long long mask = __ballot((cj >> 13) >= qthr);
            while (mask) {
                int l = __ffsll((unsigned long long)mask) - 1;
                mask &= mask - 1;
                unsigned cwd = (unsigned)__shfl((int)cj, l, 64);
                int k = K_CODES - 1 - (int)(cwd & 0x1FFFu);
                float4 wr = *(const float4*)(w + (size_t)k * DIM + lane * 4);
                float s = 0.f, h = 0.f;
                {
                    const float* zr = z + (size_t)wid * DIM + lane * 4;
                    float4 zv = *(const float4*)zr;
                    s = zv.x * wr.x + zv.y * wr.y + zv.z * wr.z + zv.w * wr.w;
                    h = wr.x * wr.x + wr.y * wr.y + wr.z * wr.z + wr.w * wr.w;
                }
                #pragma unroll
                for (int m = 32; m >= 1; m >>= 1) {
                    s += __shfl_xor(s, m, 64);
                    h += __shfl_xor(h, m, 64);
                }
                float sc = s - 0.5f * h;
                unsigned u = __float_as_uint(sc);
                u = (u & 0x80000000u) ? ~u : (u | 0x80000000u);
                unsigned long long key = ((unsigned long long)u << 32)
                                       | (unsigned)(K_CODES - 1 - k);
                bool better = key > best;             // wave-uniform
                best = better ? key : best;
                bsc  = better ? sc  : bsc;
            }
        }
        idx = K_CODES - 1 - (int)(unsigned)(best & 0xFFFFFFFFull);
        scf = bsc;
    }

    if (lane == 0) {
        out[OFF_IDX + wid] = (float)idx;
        lossp[wid] = zn2[wid] - 2.0f * scf;
        atomicAdd(cnt + idx, 1u);
    }
}

// ---- 4. single-block: scan + new_cs + n + loss + fill (cursor in LDS) -------
__global__ __launch_bounds__(1024) void k_prefix(const float* __restrict__ csin,
                                                 float* __restrict__ out,
                                                 const unsigned* __restrict__ cnt,
                                                 unsigned* __restrict__ offs,
                                                 unsigned* __restrict__ list,
                                                 const float* __restrict__ lossp,
                                                 float* __restrict__ nval) {
    __shared__ unsigned scur[K_CODES];     // 32 KB LDS cursor
    __shared__ unsigned wtot[16], wbase[16];
    __shared__ float fred[16], fred2[16];
    int t = threadIdx.x, lane = t & 63, wv = t >> 6;
    int base = t * 8;
    unsigned c[8], mysum = 0;
    #pragma unroll
    for (int i = 0; i < 8; i++) { c[i] = cnt[base + i]; mysum += c[i]; }
    unsigned inc = mysum;
    #pragma unroll
    for (int off = 1; off < 64; off <<= 1) {
        unsigned v = (unsigned)__shfl_up((int)inc, off, 64);
        if (lane >= off) inc += v;
    }
    if (lane == 63) wtot[wv] = inc;
    __syncthreads();
    if (t == 0) {
        unsigned r = 0;
        for (int i = 0; i < 16; i++) { wbase[i] = r; r += wtot[i]; }
        offs[K_CODES] = r;
    }
    __syncthreads();
    unsigned my0 = wbase[wv] + inc - mysum;
    float csl = 0.f;
    #pragma unroll
    for (int i = 0; i < 8; i++) {
        offs[base + i] = my0;
        scur[base + i] = my0;
        my0 += c[i];
        float ncs = DECAYF * csin[base + i] + OMDF * (float)c[i];
        out[OFF_CS + base + i] = ncs;
        csl += ncs;
    }
    #pragma unroll
    for (int m = 32; m >= 1; m >>= 1) csl += __shfl_xor(csl, m, 64);
    if (lane == 0) fred[wv] = csl;
    float lp = 0.f;
    #pragma unroll
    for (int i = 0; i < 16; i++) lp += lossp[t + i * 1024];
    #pragma unroll
    for (int m = 32; m >= 1; m >>= 1) lp += __shfl_xor(lp, m, 64);
    if (lane == 0) fred2[wv] = lp;
    __syncthreads();
    if (t == 0) {
        float n = 0.f, L = 0.f;
        for (int i = 0; i < 16; i++) { n += fred[i]; L += fred2[i]; }
        *nval = n;
        out[OFF_LOSS] = L * (1.0f / ((float)N_PTS * DIM));
    }
    // fill phase: LDS-atomic cursors, scattered list writes
    for (int i = t; i < N_PTS; i += 1024) {
        int idx = (int)out[OFF_IDX + i];
        unsigned pos = atomicAdd(&scur[idx], 1u);
        list[pos] = (unsigned)i;
    }
}

// ---- 5. per-code gather: z_q scatter + new_ea + new_weight (no atomics) -----
__global__ void k_gather(const float* __restrict__ z, const float* __restrict__ ea,
                         const float* __restrict__ w,
                         float* __restrict__ out,
                         const unsigned* __restrict__ offs,
                         const unsigned* __restrict__ list,
                         const float* __restrict__ nval) {
    int k = blockIdx.x, lane = threadIdx.x;
    unsigned beg = offs[k], end = offs[k + 1];
    float4 wv = *(const float4*)(w + (size_t)k * DIM + lane * 4);
    float4 acc = {0.f, 0.f, 0.f, 0.f};
    for (unsigned p = beg; p < end; ++p) {
        unsigned i = list[p];
        float4 zv = *(const float4*)(z + (size_t)i * DIM + lane * 4);
        acc.x += zv.x; acc.y += zv.y; acc.z += zv.z; acc.w += zv.w;
        *(float4*)(out + OFF_ZQ + (size_t)i * DIM + lane * 4) = wv;  // z_q = w[idx]
    }
    float4 e = *(const float4*)(ea + (size_t)k * DIM + lane * 4);
    e.x = DECAYF * e.x + OMDF * acc.x;
    e.y = DECAYF * e.y + OMDF * acc.y;
    e.z = DECAYF * e.z + OMDF * acc.z;
    e.w = DECAYF * e.w + OMDF * acc.w;
    *(float4*)(out + OFF_EA + (size_t)k * DIM + lane * 4) = e;

    float cs = out[OFF_CS + k];
    float n  = *nval;
    float inv = 1.f / ((cs + EPSF) / (n + (float)K_CODES * EPSF) * n);
    float4 wr = {e.x * inv, e.y * inv, e.z * inv, e.w * inv};
    *(float4*)(out + OFF_W + (size_t)k * DIM + lane * 4) = wr;
}

extern "C" void kernel_launch(void* const* d_in, const int* in_sizes, int n_in,
                              void* d_out, int out_size, void* d_ws, size_t ws_size,
                              hipStream_t stream) {
    const float* z  = (const float*)d_in[0];
    const float* w  = (const float*)d_in[1];
    const float* cs = (const float*)d_in[2];
    const float* ea = (const float*)d_in[3];
    float* out = (float*)d_out;

    short*    zb  = (short*)(out + ZB_OFF);
    short*    wb  = (short*)(out + WB_OFF);
    float*    hen = out + HEN_OFF;
    unsigned* c1  = (unsigned*)(out + C1_OFF);
    unsigned* c2  = (unsigned*)(out + C2_OFF);

    // small scratch in d_ws (~262 KB)
    unsigned* cnt   = (unsigned*)d_ws;        // 8192
    unsigned* offs  = cnt + 8192;             // 8193 (padded to 8200)
    unsigned* list  = offs + 8200;            // 16384
    float*    lossp = (float*)(list + 16384); // 16384
    float*    nval  = lossp + 16384;          // 1
    float*    zn2   = nval + 1;               // 16384

    hipLaunchKernelGGL(k_cvt2,    dim3((N_PTS + K_CODES) * DIM / 2048), dim3(256), 0, stream,
                       z, zb, w, wb, hen, cnt, zn2);
    hipLaunchKernelGGL(k_gemm,    dim3((N_PTS / 128) * (K_CODES / 128)), dim3(256), 0, stream,
                       zb, wb, hen, c1, c2);
    hipLaunchKernelGGL(k_rescore, dim3(N_PTS / 16),           dim3(1024), 0, stream,
                       z, w, c1, c2, zn2, out, cnt, lossp);
    hipLaunchKernelGGL(k_prefix,  dim3(1),                    dim3(1024), 0, stream,
                       cs, out, cnt, offs, list, lossp, nval);
    hipLaunchKernelGGL(k_gather,  dim3(K_CODES),              dim3(64), 0, stream,
                       z, ea, w, out, offs, list, nval);
}